// Round 2
// baseline (1018.027 us; speedup 1.0000x reference)
//
#include <hip/hip_runtime.h>
#include <hip/hip_bf16.h>

#define N_NODES 50000
#define N_EDGES 1600000
#define MERGED  153
#define NPB     16
#define EPSV    1e-8f

__device__ __forceinline__ float sigmoidf_(float x) { return 1.0f / (1.0f + __expf(-x)); }

// ---------------------------------------------------------------------------
// Kernel 1: scatter-mean prep. Fsum[n][3][3] += frames[e], deg[n] += 1
// for every edge e with row[e]==n. This is the ONLY edge-level work needed:
// both reference edge stages factor into (mean frame per node) x (per-node
// tensors), because gather index == scatter index == row:
//   sh[n]  = Fbar[n] applied to vdf[n]
//   gv[n]  = gate[n] applied to Fbar[n]
// ---------------------------------------------------------------------------
__global__ void scatter_frames_kernel(const float* __restrict__ frames,
                                      const int* __restrict__ row,
                                      float* __restrict__ Fsum,
                                      float* __restrict__ deg) {
    int e = blockIdx.x * 256 + threadIdx.x;
    if (e >= N_EDGES) return;
    int r = row[e];
    const float* f = frames + (size_t)e * 9;
#pragma unroll
    for (int k = 0; k < 9; k++) atomicAdd(&Fsum[r * 9 + k], f[k]);
    atomicAdd(&deg[r], 1.0f);
}

// ---------------------------------------------------------------------------
// Kernel 2: all per-node algebra. 16 nodes per 256-thread block.
// ---------------------------------------------------------------------------
__global__ __launch_bounds__(256) void node_kernel(
    const float* __restrict__ s,
    const float* __restrict__ v,
    const float* __restrict__ W_vd,
    const float* __restrict__ W_vdf,
    const float* __restrict__ W_so,
    const float* __restrict__ b_so,
    const float* __restrict__ W_vu,
    const float* __restrict__ W_vosf,
    const float* __restrict__ b_vosf,
    const float* __restrict__ W_vuf,
    const float* __restrict__ Fsum,
    const float* __restrict__ deg,
    float* __restrict__ out0,
    float* __restrict__ out1)
{
    __shared__ float vL[NPB][48];        // v[n][i][c] as f32
    __shared__ float vhL[NPB][3][16];    // vh[c][h]
    __shared__ float mergedL[NPB][160];  // [s(128) | vnorm(16) | sh(9) | pad]
    __shared__ float FbarL[NPB][9];      // mean frame, [i*3+j]
    __shared__ float vdfL[NPB][9];       // vdf[j][c] at [j*3+c] (j spatial, c svod)
    __shared__ float sigL[NPB][128];     // sigmoid(scalar_rep)
    __shared__ float gateL[NPB][12];     // gate[9], padded

    const int t = threadIdx.x;
    const int base = blockIdx.x * NPB;

    // ---- phase 1a: stage v and s into LDS ----
    {
        int nn = t >> 4, h = t & 15;
        int n = base + nn;
#pragma unroll
        for (int r = 0; r < 3; r++) vL[nn][h * 3 + r] = v[(size_t)n * 48 + h * 3 + r];
#pragma unroll
        for (int r = 0; r < 8; r++) mergedL[nn][h * 8 + r] = s[(size_t)n * 128 + h * 8 + r];
    }
    __syncthreads();

    // ---- phase 1b: vh, vnorm, Fbar, vdf ----
    {
        int nn = t >> 4, h = t & 15;
        int n = base + nn;
        float vh0 = 0.f, vh1 = 0.f, vh2 = 0.f;
#pragma unroll
        for (int i = 0; i < 16; i++) {
            float w = W_vd[i * 16 + h];
            vh0 += vL[nn][i * 3 + 0] * w;
            vh1 += vL[nn][i * 3 + 1] * w;
            vh2 += vL[nn][i * 3 + 2] * w;
        }
        vhL[nn][0][h] = vh0; vhL[nn][1][h] = vh1; vhL[nn][2][h] = vh2;
        mergedL[nn][128 + h] = sqrtf(vh0 * vh0 + vh1 * vh1 + vh2 * vh2 + EPSV);
        if (h < 9) {
            float inv = 1.0f / fmaxf(deg[n], 1.0f);
            FbarL[nn][h] = Fsum[n * 9 + h] * inv;
        }
        if (h < 3) {
            int cc = h;  // svod channel
#pragma unroll
            for (int j = 0; j < 3; j++) {  // spatial
                float a = 0.f;
#pragma unroll
                for (int i = 0; i < 16; i++) a += vL[nn][i * 3 + j] * W_vdf[i * 3 + cc];
                vdfL[nn][j * 3 + cc] = a;
            }
        }
    }
    __syncthreads();

    // ---- phase 1c: sh[c*3+i] = sum_j Fbar[i][j] * vdf[j][c]; zero-pad merged ----
    {
        int nn = t >> 4, h = t & 15;
        if (h < 9) {
            int c = h / 3, i = h % 3;
            float a = 0.f;
#pragma unroll
            for (int j = 0; j < 3; j++) a += FbarL[nn][i * 3 + j] * vdfL[nn][j * 3 + c];
            mergedL[nn][144 + h] = a;
        } else {
            mergedL[nn][144 + h] = 0.0f;  // pads 153..159
        }
    }
    __syncthreads();

    // ---- phase 2: scalar_rep = merged @ W_so + b_so; relu out; sigmoid to LDS ----
    {
        int o = t & 127, half = t >> 7;
        float acc[8];
        float b = b_so[o];
#pragma unroll
        for (int q = 0; q < 8; q++) acc[q] = b;
        for (int k = 0; k < MERGED; k++) {
            float w = W_so[k * 128 + o];  // one global read, reused for 8 nodes
#pragma unroll
            for (int q = 0; q < 8; q++) acc[q] += mergedL[half + 2 * q][k] * w;
        }
#pragma unroll
        for (int q = 0; q < 8; q++) {
            int nn = half + 2 * q;
            int n = base + nn;
            out0[(size_t)n * 128 + o] = fmaxf(acc[q], 0.0f);
            sigL[nn][o] = sigmoidf_(acc[q]);
        }
    }
    __syncthreads();

    // ---- gate = sigmoid(sr) @ W_vosf + b_vosf ----
    if (t < NPB * 9) {
        int nn = t / 9, k = t % 9;
        float a = b_vosf[k];
        for (int o = 0; o < 128; o++) a += sigL[nn][o] * W_vosf[o * 9 + k];
        gateL[nn][k] = a;
    }
    __syncthreads();

    // ---- phase 3: vector path ----
    {
        int nn = t >> 4, o = t & 15;
        int n = base + nn;
        float gv[9];
#pragma unroll
        for (int i = 0; i < 3; i++)
#pragma unroll
            for (int kk = 0; kk < 3; kk++) {
                float a = 0.f;
#pragma unroll
                for (int j = 0; j < 3; j++) a += gateL[nn][j * 3 + i] * FbarL[nn][j * 3 + kk];
                gv[i * 3 + kk] = a;
            }
        float gvr[3];
#pragma unroll
        for (int kk = 0; kk < 3; kk++) {
            float a = 0.f;
#pragma unroll
            for (int i = 0; i < 3; i++) a += gv[i * 3 + kk] * W_vuf[i * 16 + o];
            gvr[kk] = a;
        }
        float gn = sqrtf(gvr[0] * gvr[0] + gvr[1] * gvr[1] + gvr[2] * gvr[2] + EPSV);
        float sg = sigmoidf_(gn);
#pragma unroll
        for (int c = 0; c < 3; c++) {
            float a = 0.f;
#pragma unroll
            for (int h2 = 0; h2 < 16; h2++) a += vhL[nn][c][h2] * W_vu[h2 * 16 + o];
            out1[(size_t)n * 48 + o * 3 + c] = a * sg;
        }
    }
}

extern "C" void kernel_launch(void* const* d_in, const int* in_sizes, int n_in,
                              void* d_out, int out_size, void* d_ws, size_t ws_size,
                              hipStream_t stream) {
    const float* s      = (const float*)d_in[0];
    const float* v      = (const float*)d_in[1];
    const float* frames = (const float*)d_in[2];
    const float* W_vd   = (const float*)d_in[3];
    const float* W_vdf  = (const float*)d_in[4];
    const float* W_so   = (const float*)d_in[5];
    const float* b_so   = (const float*)d_in[6];
    const float* W_vu   = (const float*)d_in[7];
    const float* W_vosf = (const float*)d_in[8];
    const float* b_vosf = (const float*)d_in[9];
    const float* W_vuf  = (const float*)d_in[10];
    const int* edge_index = (const int*)d_in[11];
    // d_in[12] = node_inputs (assumed truthy, per reference)

    float* Fsum = (float*)d_ws;
    float* deg  = Fsum + (size_t)N_NODES * 9;
    float* out0 = (float*)d_out;
    float* out1 = out0 + (size_t)N_NODES * 128;

    hipMemsetAsync(d_ws, 0, (size_t)N_NODES * 10 * sizeof(float), stream);
    scatter_frames_kernel<<<(N_EDGES + 255) / 256, 256, 0, stream>>>(
        frames, edge_index, Fsum, deg);
    node_kernel<<<N_NODES / NPB, 256, 0, stream>>>(
        s, v, W_vd, W_vdf, W_so, b_so, W_vu, W_vosf, b_vosf, W_vuf,
        Fsum, deg, out0, out1);
}